// Round 2
// baseline (108.091 us; speedup 1.0000x reference)
//
#include <hip/hip_runtime.h>
#include <math.h>

// ============================================================================
// PROBE ROUND: kernel launched TWICE (idempotent) to measure the matcher's
// device time via dur_us delta. The matcher never appears in rocprof top-5
// (all slots taken by ~45 µs harness poison fills), so its duration is
// unobservable directly. Delta vs the 90 µs baseline = one kernel execution.
// ============================================================================

// Problem constants (fixed by setup_inputs)
constexpr int kB = 16, kN = 900, kC = 92, kT = 960;
constexpr int kBN = kB * kN;          // 14400 rows
constexpr int ROWS = 4;               // rows per block (one wave each for softmax)
constexpr int THREADS = 256;

typedef float nt_float4 __attribute__((ext_vector_type(4)));

__global__ __launch_bounds__(THREADS) void matcher_kernel(
    const float* __restrict__ out_labels,   // [BN, C]
    const float* __restrict__ out_bboxes,   // [BN, 4] cxcywh
    const int*   __restrict__ tgt_labels,   // [T]
    const float* __restrict__ tgt_bboxes,   // [T, 4] used as-is (xyxy per reference NOTE)
    float*       __restrict__ cost)         // [BN, T]
{
    __shared__ float4 s_cl4[kC];            // 1472 B, transposed class-cost table
    __shared__ float4 s_rowA[ROWS];         // cx,cy,w,h
    __shared__ float4 s_rowB[ROWS];         // bx0,by0,bx1,by1
    __shared__ float  s_rowC[ROWS];         // area1

    const int tid  = threadIdx.x;
    const int row0 = blockIdx.x * ROWS;

    const int t0 = tid * 4;
    float4 tb[4]; float a2[4]; int4 lab;
    if (t0 < kT) {
        const float4* tb4 = (const float4*)tgt_bboxes;
        #pragma unroll
        for (int i = 0; i < 4; ++i) tb[i] = tb4[t0 + i];
        lab = ((const int4*)tgt_labels)[tid];
        #pragma unroll
        for (int i = 0; i < 4; ++i)
            a2[i] = (tb[i].z - tb[i].x) * (tb[i].w - tb[i].y);
    }

    // Per-row softmax: wave r handles row r (C=92 -> lanes cover [0,64) and [64,92))
    {
        const int r = tid >> 6;
        const int lane = tid & 63;
        const int p = row0 + r;
        const float* lrow = out_labels + (size_t)p * kC;
        float x0 = (lane < kC)      ? lrow[lane]      : -INFINITY;
        float x1 = (lane + 64 < kC) ? lrow[lane + 64] : -INFINITY;
        float m = fmaxf(x0, x1);
        #pragma unroll
        for (int off = 32; off > 0; off >>= 1)
            m = fmaxf(m, __shfl_down(m, off, 64));
        m = __shfl(m, 0, 64);
        float e0 = (lane < kC)      ? __expf(x0 - m) : 0.0f;
        float e1 = (lane + 64 < kC) ? __expf(x1 - m) : 0.0f;
        float s = e0 + e1;
        #pragma unroll
        for (int off = 32; off > 0; off >>= 1)
            s += __shfl_down(s, off, 64);
        s = __shfl(s, 0, 64);
        float inv = 1.0f / s;
        float* clf = (float*)s_cl4;
        if (lane < kC)      clf[lane * 4 + r]        = 5.0f - e0 * inv;
        if (lane + 64 < kC) clf[(lane + 64) * 4 + r] = 5.0f - e1 * inv;
        if (lane == 0) {
            float4 bb = ((const float4*)out_bboxes)[p];
            float hw = 0.5f * bb.z, hh = 0.5f * bb.w;
            float bx0 = bb.x - hw, by0 = bb.y - hh;
            float bx1 = bb.x + hw, by1 = bb.y + hh;
            s_rowA[r] = bb;
            s_rowB[r] = make_float4(bx0, by0, bx1, by1);
            s_rowC[r] = (bx1 - bx0) * (by1 - by0);
        }
    }
    __syncthreads();

    if (t0 < kT) {
        float4 cls[4];
        cls[0] = s_cl4[lab.x];
        cls[1] = s_cl4[lab.y];
        cls[2] = s_cl4[lab.z];
        cls[3] = s_cl4[lab.w];
        #pragma unroll
        for (int r = 0; r < ROWS; ++r) {
            const int p = row0 + r;
            float4 ra = s_rowA[r];
            float4 rb = s_rowB[r];
            float area1 = s_rowC[r];
            nt_float4 res;
            #pragma unroll
            for (int i = 0; i < 4; ++i) {
                float4 t = tb[i];
                float l1 = fabsf(ra.x - t.x) + fabsf(ra.y - t.y)
                         + fabsf(ra.z - t.z) + fabsf(ra.w - t.w);
                float ltx = fmaxf(rb.x, t.x), lty = fmaxf(rb.y, t.y);
                float rbx = fminf(rb.z, t.z), rby = fminf(rb.w, t.w);
                float iw = fmaxf(rbx - ltx, 0.0f), ih = fmaxf(rby - lty, 0.0f);
                float inter = iw * ih;
                float uni = area1 + a2[i] - inter;
                float ex0 = fminf(rb.x, t.x), ey0 = fminf(rb.y, t.y);
                float ex1 = fmaxf(rb.z, t.z), ey1 = fmaxf(rb.w, t.w);
                float area_e = (ex1 - ex0) * (ey1 - ey0);
                float num = fmaf(uni, uni, inter * area_e);
                float rcp = __builtin_amdgcn_rcpf(uni * area_e);
                float v = (r == 0) ? cls[i].x : (r == 1) ? cls[i].y
                        : (r == 2) ? cls[i].z : cls[i].w;
                v = fmaf(5.0f, l1, v);
                v = fmaf(-2.0f * num, rcp, v);
                res[i] = v;
            }
            __builtin_nontemporal_store(res, (nt_float4*)(cost + (size_t)p * kT) + tid);
        }
    }
}

extern "C" void kernel_launch(void* const* d_in, const int* in_sizes, int n_in,
                              void* d_out, int out_size, void* d_ws, size_t ws_size,
                              hipStream_t stream) {
    const float* out_labels = (const float*)d_in[0];
    const float* out_bboxes = (const float*)d_in[1];
    const int*   tgt_labels = (const int*)d_in[2];
    const float* tgt_bboxes = (const float*)d_in[3];
    float* cost = (float*)d_out;
    dim3 grid(kBN / ROWS);   // 14400/4 = 3600 blocks
    // PROBE: two identical launches. Idempotent (pure function of inputs ->
    // same output written twice). dur_us delta vs 90 µs baseline == one
    // matcher execution's device time.
    matcher_kernel<<<grid, THREADS, 0, stream>>>(out_labels, out_bboxes,
                                                 tgt_labels, tgt_bboxes, cost);
    matcher_kernel<<<grid, THREADS, 0, stream>>>(out_labels, out_bboxes,
                                                 tgt_labels, tgt_bboxes, cost);
}

// Round 3
// 89.621 us; speedup vs baseline: 1.2061x; 1.2061x over previous
//
#include <hip/hip_runtime.h>
#include <math.h>

// Problem constants (fixed by setup_inputs)
constexpr int kB = 16, kN = 900, kC = 92, kT = 960;
constexpr int kBN = kB * kN;          // 14400 rows
constexpr int ROWS = 8;               // rows per block (one wave each for softmax)
constexpr int THREADS = 512;          // 8 waves; pair phase: 2 targets/thread

typedef float vf2 __attribute__((ext_vector_type(2)));

// Probe evidence (R2): matcher = 17.6 us/launch, harness fixed overhead = 72.9 us.
// Floor = max(9.7 us mandatory HBM traffic, ~8 us VALU) ~ 10-12 us.
// This version attacks the latency/overlap gap: halved per-thread register
// state + __launch_bounds__(512,6) -> >=24 waves/CU (vs ~16-20 unhinted),
// so cold label reads + barriers of one block hide under other blocks' pair
// phases. Store path proven irrelevant (NT vs cached identical at 90 us).
__global__ __launch_bounds__(THREADS, 6) void matcher_kernel(
    const float* __restrict__ out_labels,   // [BN, C]
    const float* __restrict__ out_bboxes,   // [BN, 4] cxcywh
    const int*   __restrict__ tgt_labels,   // [T]
    const float* __restrict__ tgt_bboxes,   // [T, 4] used as-is (xyxy per reference NOTE)
    float*       __restrict__ cost)         // [BN, T]
{
    // Class-cost tables TRANSPOSED: s_clA[c] = {5-prob_r0(c),..,5-prob_r3(c)},
    // s_clB[c] = rows 4..7. One ds_read_b128 gather serves 4 rows.
    __shared__ float4 s_clA[kC];            // 1472 B
    __shared__ float4 s_clB[kC];            // 1472 B
    __shared__ float4 s_rowA[ROWS];         // cx,cy,w,h
    __shared__ float4 s_rowB[ROWS];         // bx0,by0,bx1,by1
    __shared__ float  s_rowC[ROWS];         // area1

    const int tid  = threadIdx.x;
    const int row0 = blockIdx.x * ROWS;

    // Targets: thread owns 2 consecutive targets, held in regs across all 8
    // rows. 19 KB total -> L1-resident per CU after first block.
    const int t0 = tid * 2;
    float4 tb[2]; float a2[2]; int2 lab;
    if (t0 < kT) {
        const float4* tb4 = (const float4*)tgt_bboxes;
        tb[0] = tb4[t0];
        tb[1] = tb4[t0 + 1];
        lab = ((const int2*)tgt_labels)[tid];
        a2[0] = (tb[0].z - tb[0].x) * (tb[0].w - tb[0].y);
        a2[1] = (tb[1].z - tb[1].x) * (tb[1].w - tb[1].y);
    }

    // Per-row softmax: wave r handles row r (C=92 -> lanes cover [0,64) and [64,92))
    {
        const int r = tid >> 6;             // 0..7
        const int lane = tid & 63;
        const int p = row0 + r;
        const float* lrow = out_labels + (size_t)p * kC;
        float x0 = (lane < kC)      ? lrow[lane]      : -INFINITY;
        float x1 = (lane + 64 < kC) ? lrow[lane + 64] : -INFINITY;
        float m = fmaxf(x0, x1);
        #pragma unroll
        for (int off = 32; off > 0; off >>= 1)
            m = fmaxf(m, __shfl_down(m, off, 64));
        m = __shfl(m, 0, 64);
        float e0 = (lane < kC)      ? __expf(x0 - m) : 0.0f;
        float e1 = (lane + 64 < kC) ? __expf(x1 - m) : 0.0f;
        float s = e0 + e1;
        #pragma unroll
        for (int off = 32; off > 0; off >>= 1)
            s += __shfl_down(s, off, 64);
        s = __shfl(s, 0, 64);
        float inv = 1.0f / s;
        // transposed write: class c, row r&3 -> flat [c*4 + (r&3)] in A or B
        float* clf = (r < 4) ? (float*)s_clA : (float*)s_clB;
        const int rr = r & 3;
        if (lane < kC)      clf[lane * 4 + rr]        = 5.0f - e0 * inv;
        if (lane + 64 < kC) clf[(lane + 64) * 4 + rr] = 5.0f - e1 * inv;
        if (lane == 0) {
            float4 bb = ((const float4*)out_bboxes)[p];
            float hw = 0.5f * bb.z, hh = 0.5f * bb.w;
            float bx0 = bb.x - hw, by0 = bb.y - hh;
            float bx1 = bb.x + hw, by1 = bb.y + hh;
            s_rowA[r] = bb;
            s_rowB[r] = make_float4(bx0, by0, bx1, by1);
            s_rowC[r] = (bx1 - bx0) * (by1 - by0);   // area1, same order as ref
        }
    }
    __syncthreads();

    // Pair phase: each thread owns 2 consecutive targets, loops 8 rows.
    if (t0 < kT) {
        float4 cls0 = s_clA[lab.x];   // 1 b128 gather -> 4 rows' class costs
        float4 cls1 = s_clA[lab.y];
        #pragma unroll
        for (int r = 0; r < ROWS; ++r) {
            if (r == 4) {             // re-gather for rows 4..7 (reuses regs)
                cls0 = s_clB[lab.x];
                cls1 = s_clB[lab.y];
            }
            const int p = row0 + r;
            float4 ra = s_rowA[r];          // cx,cy,w,h   (LDS broadcast)
            float4 rb = s_rowB[r];          // bx0,by0,bx1,by1
            float area1 = s_rowC[r];
            const int rr = r & 3;
            vf2 res;
            #pragma unroll
            for (int i = 0; i < 2; ++i) {
                float4 t = tb[i];
                // L1 on raw cxcywh vs target (torch.cdist p=1 semantics)
                float l1 = fabsf(ra.x - t.x) + fabsf(ra.y - t.y)
                         + fabsf(ra.z - t.z) + fabsf(ra.w - t.w);
                // intersection (clamp needed)
                float ltx = fmaxf(rb.x, t.x), lty = fmaxf(rb.y, t.y);
                float rbx = fminf(rb.z, t.z), rby = fminf(rb.w, t.w);
                float iw = fmaxf(rbx - ltx, 0.0f), ih = fmaxf(rby - lty, 0.0f);
                float inter = iw * ih;
                float uni = area1 + a2[i] - inter;
                // enclosing box (clamp is a no-op: pred w,h >= 0)
                float ex0 = fminf(rb.x, t.x), ey0 = fminf(rb.y, t.y);
                float ex1 = fmaxf(rb.z, t.z), ey1 = fmaxf(rb.w, t.w);
                float area_e = (ex1 - ex0) * (ey1 - ey0);
                // cost = (5-prob) + 5*L1 - 2*(inter*area_e + uni^2)/(uni*area_e)
                float num = fmaf(uni, uni, inter * area_e);
                float rcp = __builtin_amdgcn_rcpf(uni * area_e);
                float4 cls = i == 0 ? cls0 : cls1;
                float v = (rr == 0) ? cls.x : (rr == 1) ? cls.y
                        : (rr == 2) ? cls.z : cls.w;
                v = fmaf(5.0f, l1, v);
                v = fmaf(-2.0f * num, rcp, v);
                res[i] = v;
            }
            // 8 B/lane, 512 B/wave contiguous -> fully coalesced
            *((vf2*)(cost + (size_t)p * kT + t0)) = res;
        }
    }
}

extern "C" void kernel_launch(void* const* d_in, const int* in_sizes, int n_in,
                              void* d_out, int out_size, void* d_ws, size_t ws_size,
                              hipStream_t stream) {
    const float* out_labels = (const float*)d_in[0];
    const float* out_bboxes = (const float*)d_in[1];
    const int*   tgt_labels = (const int*)d_in[2];
    const float* tgt_bboxes = (const float*)d_in[3];
    float* cost = (float*)d_out;
    dim3 grid(kBN / ROWS);   // 14400/8 = 1800 blocks
    matcher_kernel<<<grid, THREADS, 0, stream>>>(out_labels, out_bboxes,
                                                 tgt_labels, tgt_bboxes, cost);
}